// Round 11
// baseline (1314.777 us; speedup 1.0000x reference)
//
#include <hip/hip_runtime.h>

// PointNet++ Set Abstraction for MI355X (gfx950).
// prep -> FPS -> ball-query -> L0(mfma) -> stat -> L1 -> stat -> L2(+pool) -> stat -> final.
// FPS replicates reference f32 elementwise arithmetic exactly (non-FMA, same order).
// Ball-query dot uses an FMA chain replicating BLAS sgemm accumulation.
// Activations stored f32; GEMMs use hi/lo split-bf16 MFMA (near-f32).
// R10: FPS distance loop forced to v_pk_add_f32/v_pk_mul_f32 via inline asm
// (IEEE per-lane == scalar, same op order -> bit-exact); ballq LDS staging
// removed (data is L2-resident; staging was pure overhead + occupancy cap).

typedef __bf16 bf16x8 __attribute__((ext_vector_type(8)));
typedef float f32x4 __attribute__((ext_vector_type(4)));
typedef float f32x2 __attribute__((ext_vector_type(2)));

#define B_ 16
#define N_ 8192
#define S_ 1024
#define K_ 32
#define M_ 524288   // B*S*K rows
#define NBLK_ 4096  // M/128

__device__ __forceinline__ f32x4 mfma16(bf16x8 a, bf16x8 b, f32x4 c) {
  return __builtin_amdgcn_mfma_f32_16x16x32_bf16(a, b, c, 0, 0, 0);
}

__device__ __forceinline__ void split8(const float* v, bf16x8& hi, bf16x8& lo) {
#pragma unroll
  for (int e = 0; e < 8; ++e) {
    __bf16 h = (__bf16)v[e];
    hi[e] = h;
    lo[e] = (__bf16)(v[e] - (float)h);
  }
}

// Packed f32 ops forced via VOP3P inline asm. Per-lane IEEE identical to the
// scalar v_sub/v_mul/v_add sequence -> bit-exact vs reference order.
__device__ __forceinline__ f32x2 pk_sub(f32x2 a, f32x2 b) {
  f32x2 r;
  asm("v_pk_add_f32 %0, %1, %2 neg_lo:[0,1] neg_hi:[0,1]" : "=v"(r) : "v"(a), "v"(b));
  return r;
}
__device__ __forceinline__ f32x2 pk_mul(f32x2 a, f32x2 b) {
  f32x2 r;
  asm("v_pk_mul_f32 %0, %1, %2" : "=v"(r) : "v"(a), "v"(b));
  return r;
}
__device__ __forceinline__ f32x2 pk_add(f32x2 a, f32x2 b) {
  f32x2 r;
  asm("v_pk_add_f32 %0, %1, %2" : "=v"(r) : "v"(a), "v"(b));
  return r;
}

// Wave64 max of non-negative f32 via DPP; returns uniform max (all lanes).
// bound_ctrl=true fills invalid lanes with 0 (max-neutral for x >= 0).
__device__ __forceinline__ float wave_max_nonneg(float x) {
  int v = __float_as_int(x);
#define DPP_MAX(ctrl)                                                          \
  v = __float_as_int(fmaxf(__int_as_float(v),                                  \
        __int_as_float(__builtin_amdgcn_update_dpp(0, v, (ctrl), 0xf, 0xf, true))))
  DPP_MAX(0x111);  // row_shr:1
  DPP_MAX(0x112);  // row_shr:2
  DPP_MAX(0x114);  // row_shr:4
  DPP_MAX(0x118);  // row_shr:8
  DPP_MAX(0x142);  // row_bcast:15
  DPP_MAX(0x143);  // row_bcast:31
#undef DPP_MAX
  return __int_as_float(__builtin_amdgcn_readlane(v, 63));
}

// ---------------- prep: packed {x,y,z,|p|^2}, hi/lo split weights ----------------
__global__ __launch_bounds__(256) void prep_kernel(
    const float* __restrict__ xyz, const float* __restrict__ w0,
    const float* __restrict__ w1, const float* __restrict__ w2,
    float4* __restrict__ sxyzp,
    __bf16* __restrict__ w0h, __bf16* __restrict__ w0l,
    __bf16* __restrict__ w1h, __bf16* __restrict__ w1l,
    __bf16* __restrict__ w2h, __bf16* __restrict__ w2l) {
#pragma clang fp contract(off)
  int gid = blockIdx.x * 256 + threadIdx.x;
  if (gid < B_ * N_) {
    float x = xyz[gid * 3 + 0], y = xyz[gid * 3 + 1], z = xyz[gid * 3 + 2];
    float p = (x * x + y * y) + z * z;  // exact reference order
    sxyzp[gid] = make_float4(x, y, z, p);
  } else {
    int j = gid - B_ * N_;
    float v; __bf16* ph; __bf16* pl; int jj;
    if (j < 6656) {            // W0: [64][104], real c<67
      int o = j / 104, c = j % 104;
      v = (c < 67) ? w0[o * 67 + c] : 0.f; ph = w0h; pl = w0l; jj = j;
    } else if (j < 6656 + 4608) {  // W1: [64][72], real c<64
      jj = j - 6656;
      int o = jj / 72, c = jj % 72;
      v = (c < 64) ? w1[o * 64 + c] : 0.f; ph = w1h; pl = w1l;
    } else if (j < 6656 + 4608 + 9216) {  // W2: [128][72]
      jj = j - 6656 - 4608;
      int o = jj / 72, c = jj % 72;
      v = (c < 64) ? w2[o * 64 + c] : 0.f; ph = w2h; pl = w2l;
    } else return;
    __bf16 h = (__bf16)v;
    ph[jj] = h;
    pl[jj] = (__bf16)(v - (float)h);
  }
}

// ---------------- FPS: one block per batch, 512 thr x 16 pts, pk-asm + DPP ----------------
__global__ __launch_bounds__(512, 1) void fps_kernel(
    const float4* __restrict__ sxyzp, float* __restrict__ out /* new_xyz (B,S,3) */) {
#pragma clang fp contract(off)
  const int b = blockIdx.x;
  const int t = threadIdx.x;
  __shared__ float4 sp[N_];                    // 128 KB (centroid lookup)
  __shared__ int farhist[S_];                  // 4 KB winner history
  __shared__ uint2 went[2][8];                 // {val_bits, idx} per wave, double-buffered
  const float4* src = sxyzp + (size_t)b * N_;
  for (int i = t; i < N_; i += 512) sp[i] = src[i];
  __syncthreads();
  // contiguous chunk per lane: thread t owns points [16t, 16t+16), packed in pairs
  f32x2 px[8], py[8], pz[8], dd[8];
  const int i0 = t * 16;
#pragma unroll
  for (int w = 0; w < 16; ++w) {
    float4 v = sp[i0 + w];
    px[w >> 1][w & 1] = v.x; py[w >> 1][w & 1] = v.y; pz[w >> 1][w & 1] = v.z;
  }
#pragma unroll
  for (int j = 0; j < 8; ++j) dd[j] = (f32x2){1e10f, 1e10f};
  const int lane = t & 63, wid = t >> 6;
  int far = 0;
  for (int s = 0; s < S_; ++s) {
    if (t == 0) farhist[s] = far;              // LDS only; no global store in loop
    float4 c = sp[far];
    const f32x2 cx = {c.x, c.x}, cy = {c.y, c.y}, cz = {c.z, c.z};
    f32x2 bv2 = {-1.0f, -1.0f};
#pragma unroll
    for (int j = 0; j < 8; ++j) {
      f32x2 dx = pk_sub(px[j], cx);
      f32x2 dy = pk_sub(py[j], cy);
      f32x2 dz = pk_sub(pz[j], cz);
      // exact reference order: (dx*dx + dy*dy) + dz*dz, no fma
      f32x2 d = pk_add(pk_add(pk_mul(dx, dx), pk_mul(dy, dy)), pk_mul(dz, dz));
      f32x2 nd = __builtin_elementwise_min(dd[j], d);
      dd[j] = nd;
      bv2 = __builtin_elementwise_max(bv2, nd);
    }
    float bv = fmaxf(bv2[0], bv2[1]);
    // first (lowest) local index equal to bv: descending select keeps lowest w
    int bi = 0;
#pragma unroll
    for (int w = 15; w >= 0; --w) if (dd[w >> 1][w & 1] == bv) bi = i0 + w;
    // wave-wide max via DPP (uniform), then lowest-lane index via SGPR readlane
    float m = wave_max_nonneg(bv);
    unsigned long long msk = __ballot(bv == m);
    int srcl = __ffsll((long long)msk) - 1;          // uniform (SGPR)
    int wbi = __builtin_amdgcn_readlane(bi, srcl);   // uniform
    if (lane == 0) went[s & 1][wid] = make_uint2(__float_as_uint(m), (unsigned)wbi);
    __syncthreads();
    // ascending wave scan, strict >: lowest wave (= lowest index) wins ties.
    // f32 order == u32 order for non-negative distances.
    uint2 bestE = went[s & 1][0];
#pragma unroll
    for (int w = 1; w < 8; ++w) {
      uint2 e = went[s & 1][w];
      if (e.x > bestE.x) bestE = e;
    }
    far = (int)bestE.y;
  }
  __syncthreads();
  // one-time output write from history (exact sp values)
  float* outB = out + (size_t)b * S_ * 3;
  for (int k = t; k < S_; k += 512) {
    float4 v = sp[farhist[k]];
    outB[k * 3 + 0] = v.x; outB[k * 3 + 1] = v.y; outB[k * 3 + 2] = v.z;
  }
}

// ---------------- ball query: 16 queries per block, NO LDS staging ----------------
// sxyzp is 2 MB total (L2/L3-resident after prep); staging 128 KB/block was
// pure overhead and capped occupancy at 1 block/CU (guide common-mistake #7).
__global__ __launch_bounds__(1024) void ballq_kernel(
    const float4* __restrict__ sxyzp, const float* __restrict__ newxyz,
    int* __restrict__ idxout) {
#pragma clang fp contract(off)
  __shared__ int sel[16][32];
  const int t = threadIdx.x;
  const int g = blockIdx.x;
  const int b = g >> 6;
  const int q0 = (g & 63) << 4;
  const float4* __restrict__ sp = sxyzp + (size_t)b * N_;
  const int wid = t >> 6, lane = t & 63;
  const int q = q0 + wid;
  const float* qp = newxyz + ((size_t)b * S_ + q) * 3;
  const float qx = qp[0], qy = qp[1], qz = qp[2];
  const float qq = (qx * qx + qy * qy) + qz * qz;
  const float rr = (float)(0.4 * 0.4);
  int nsel = 0;
  for (int c0 = 0; c0 < N_ && nsel < 32; c0 += 64) {
    int i = c0 + lane;
    float4 v = sp[i];
    // BLAS-style FMA accumulation chain (matches einsum->matmul lowering):
    float dot = fmaf(qz, v.z, fmaf(qy, v.y, qx * v.x));
    float d = -2.0f * dot;
    d = d + qq;
    d = d + v.w;
    unsigned long long m = __ballot(!(d > rr));
    if ((m >> lane) & 1ull) {
      int rank = nsel + __popcll(m & ((1ull << lane) - 1ull));
      if (rank < 32) sel[wid][rank] = i;
    }
    nsel += __popcll(m);
  }
  __syncthreads();
  int nv = nsel < 32 ? nsel : 32;
  int first = sel[wid][0];
  if (lane < 32)
    idxout[(((size_t)b * S_ + q) << 5) + lane] = (lane < nv) ? sel[wid][lane] : first;
}

// ---------------- layer 0: gather+concat -> split GEMM 67->64 (K padded 96) ----------------
__global__ __launch_bounds__(256) void layer0_kernel(
    const float4* __restrict__ sxyzp, const float* __restrict__ points,
    const float* __restrict__ newxyz, const int* __restrict__ idx,
    const __bf16* __restrict__ wh, const __bf16* __restrict__ wl,
    float* __restrict__ yout, float* __restrict__ partial) {
  __shared__ __align__(16) __bf16 Ah[128 * 104];
  __shared__ __align__(16) __bf16 Al[128 * 104];
  __shared__ __align__(16) __bf16 Bh[64 * 104];
  __shared__ __align__(16) __bf16 Bl[64 * 104];
  __shared__ float swsum[4][64], swsq[4][64];
  const int t = threadIdx.x;
  const int blk = blockIdx.x;
  const size_t row0 = (size_t)blk * 128;
  {
    const int4* sh4 = (const int4*)wh;
    const int4* sl4 = (const int4*)wl;
    int4* dh4 = (int4*)Bh;
    int4* dl4 = (int4*)Bl;
    for (int k = t; k < 832; k += 256) { dh4[k] = sh4[k]; dl4[k] = sl4[k]; }
  }
  {
    const int r = t >> 1, half = t & 1;
    const size_t row = row0 + r;
    const int b = (int)(row >> 15);
    const int s = (int)((row >> 5) & 1023);
    const int i = idx[row];
    const size_t bi = (size_t)b * N_ + i;
    const float* pt = points + bi * 64;
    const float* nx = newxyz + ((size_t)b * S_ + s) * 3;
    const int jb = half ? 6 : 0, je = half ? 13 : 6;
    float gx = 0.f, gy = 0.f, gz = 0.f;
    if (!half) {
      float4 xv = sxyzp[bi];
      gx = xv.x - nx[0]; gy = xv.y - nx[1]; gz = xv.z - nx[2];
    }
#pragma unroll 13
    for (int j = jb; j < je; ++j) {
      float v[8];
#pragma unroll
      for (int e = 0; e < 8; ++e) {
        const int c = j * 8 + e;
        v[e] = (c == 0) ? gx : (c == 1) ? gy : (c == 2) ? gz
               : (c < 67) ? pt[c - 3] : 0.f;
      }
      bf16x8 hi, lo;
      split8(v, hi, lo);
      *(bf16x8*)(Ah + r * 104 + j * 8) = hi;
      *(bf16x8*)(Al + r * 104 + j * 8) = lo;
    }
  }
  __syncthreads();
  const int wid = t >> 6, lane = t & 63;
  const int wrow = wid * 32;
  const int lrow = lane & 15, lk = (lane >> 4) * 8;
  f32x4 acc[2][4];
#pragma unroll
  for (int a_ = 0; a_ < 2; ++a_)
#pragma unroll
    for (int b_ = 0; b_ < 4; ++b_) acc[a_][b_] = (f32x4){0.f, 0.f, 0.f, 0.f};
#pragma unroll
  for (int ks = 0; ks < 3; ++ks) {
    const int ko = ks * 32 + lk;
    bf16x8 ah0 = *(const bf16x8*)(Ah + (wrow + lrow) * 104 + ko);
    bf16x8 al0 = *(const bf16x8*)(Al + (wrow + lrow) * 104 + ko);
    bf16x8 ah1 = *(const bf16x8*)(Ah + (wrow + 16 + lrow) * 104 + ko);
    bf16x8 al1 = *(const bf16x8*)(Al + (wrow + 16 + lrow) * 104 + ko);
#pragma unroll
    for (int cf = 0; cf < 4; ++cf) {
      bf16x8 bh = *(const bf16x8*)(Bh + (cf * 16 + lrow) * 104 + ko);
      bf16x8 bl = *(const bf16x8*)(Bl + (cf * 16 + lrow) * 104 + ko);
      acc[0][cf] = mfma16(ah0, bh, acc[0][cf]);
      acc[0][cf] = mfma16(al0, bh, acc[0][cf]);
      acc[0][cf] = mfma16(ah0, bl, acc[0][cf]);
      acc[1][cf] = mfma16(ah1, bh, acc[1][cf]);
      acc[1][cf] = mfma16(al1, bh, acc[1][cf]);
      acc[1][cf] = mfma16(ah1, bl, acc[1][cf]);
    }
  }
#pragma unroll
  for (int cf = 0; cf < 4; ++cf) {
    float s = 0.f, s2 = 0.f;
    const int col = cf * 16 + lrow;
#pragma unroll
    for (int rf = 0; rf < 2; ++rf) {
      const int rbase = wrow + rf * 16 + (lane >> 4) * 4;
#pragma unroll
      for (int q = 0; q < 4; ++q) {
        float v = acc[rf][cf][q];
        yout[(row0 + rbase + q) * 64 + col] = v;
        s += v; s2 += v * v;
      }
    }
    s += __shfl_xor(s, 16, 64); s += __shfl_xor(s, 32, 64);
    s2 += __shfl_xor(s2, 16, 64); s2 += __shfl_xor(s2, 32, 64);
    if ((lane >> 4) == 0) { swsum[wid][col] = s; swsq[wid][col] = s2; }
  }
  __syncthreads();
  if (t < 128) {
    const int c = t & 63;
    float v = (t < 64) ? (swsum[0][c] + swsum[1][c] + swsum[2][c] + swsum[3][c])
                       : (swsq[0][c] + swsq[1][c] + swsq[2][c] + swsq[3][c]);
    partial[(size_t)t * NBLK_ + blk] = v;
  }
}

// ---------------- stat: mean/var -> (a, shift) ----------------
__global__ __launch_bounds__(64) void stat_kernel(
    const float* __restrict__ partial, const float* __restrict__ g,
    const float* __restrict__ bt, float* __restrict__ ab, int nch) {
  const int o = blockIdx.x, t = threadIdx.x;
  float s = 0.f, s2 = 0.f;
  for (int i = t; i < NBLK_; i += 64) {
    s += partial[(size_t)o * NBLK_ + i];
    s2 += partial[(size_t)(nch + o) * NBLK_ + i];
  }
#pragma unroll
  for (int off = 32; off >= 1; off >>= 1) {
    s += __shfl_xor(s, off, 64);
    s2 += __shfl_xor(s2, off, 64);
  }
  if (t == 0) {
    const float minv = 1.0f / (float)M_;
    float mean = s * minv;
    float var = s2 * minv - mean * mean;
    float a = g[o] * rsqrtf(var + 1e-5f);
    ab[o] = a;
    ab[128 + o] = bt[o] - mean * a;
  }
}

// ---------------- layer 1: BN0+ReLU on load -> split GEMM 64->64 (in-place y) ----------------
__global__ __launch_bounds__(256) void layer1_kernel(
    float* y /* f32 activations, read rows then overwritten (same block) */,
    const __bf16* __restrict__ wh, const __bf16* __restrict__ wl,
    const float* __restrict__ ab, float* __restrict__ partial) {
  __shared__ __align__(16) __bf16 Ah[128 * 72];
  __shared__ __align__(16) __bf16 Al[128 * 72];
  __shared__ __align__(16) __bf16 Bh[64 * 72];
  __shared__ __align__(16) __bf16 Bl[64 * 72];
  __shared__ float sa[64], sb[64];
  __shared__ float swsum[4][64], swsq[4][64];
  const int t = threadIdx.x;
  const int blk = blockIdx.x;
  const size_t row0 = (size_t)blk * 128;
  if (t < 64) { sa[t] = ab[t]; sb[t] = ab[128 + t]; }
  {
    const int4* sh4 = (const int4*)wh;
    const int4* sl4 = (const int4*)wl;
    int4* dh4 = (int4*)Bh;
    int4* dl4 = (int4*)Bl;
    for (int k = t; k < 576; k += 256) { dh4[k] = sh4[k]; dl4[k] = sl4[k]; }
  }
  __syncthreads();
  {
    const int r = t >> 1, half = t & 1;
    const float4* s4 = (const float4*)(y + (row0 + r) * 64 + half * 32);
#pragma unroll
    for (int j = 0; j < 4; ++j) {
      float4 u = s4[j * 2], w = s4[j * 2 + 1];
      float v[8] = {u.x, u.y, u.z, u.w, w.x, w.y, w.z, w.w};
#pragma unroll
      for (int e = 0; e < 8; ++e) {
        const int c = half * 32 + j * 8 + e;
        v[e] = fmaxf(v[e] * sa[c] + sb[c], 0.f);
      }
      bf16x8 hi, lo;
      split8(v, hi, lo);
      *(bf16x8*)(Ah + r * 72 + half * 32 + j * 8) = hi;
      *(bf16x8*)(Al + r * 72 + half * 32 + j * 8) = lo;
    }
  }
  __syncthreads();
  const int wid = t >> 6, lane = t & 63;
  const int wrow = wid * 32;
  const int lrow = lane & 15, lk = (lane >> 4) * 8;
  f32x4 acc[2][4];
#pragma unroll
  for (int a_ = 0; a_ < 2; ++a_)
#pragma unroll
    for (int b_ = 0; b_ < 4; ++b_) acc[a_][b_] = (f32x4){0.f, 0.f, 0.f, 0.f};
#pragma unroll
  for (int ks = 0; ks < 2; ++ks) {
    const int ko = ks * 32 + lk;
    bf16x8 ah0 = *(const bf16x8*)(Ah + (wrow + lrow) * 72 + ko);
    bf16x8 al0 = *(const bf16x8*)(Al + (wrow + lrow) * 72 + ko);
    bf16x8 ah1 = *(const bf16x8*)(Ah + (wrow + 16 + lrow) * 72 + ko);
    bf16x8 al1 = *(const bf16x8*)(Al + (wrow + 16 + lrow) * 72 + ko);
#pragma unroll
    for (int cf = 0; cf < 4; ++cf) {
      bf16x8 bh = *(const bf16x8*)(Bh + (cf * 16 + lrow) * 72 + ko);
      bf16x8 bl = *(const bf16x8*)(Bl + (cf * 16 + lrow) * 72 + ko);
      acc[0][cf] = mfma16(ah0, bh, acc[0][cf]);
      acc[0][cf] = mfma16(al0, bh, acc[0][cf]);
      acc[0][cf] = mfma16(ah0, bl, acc[0][cf]);
      acc[1][cf] = mfma16(ah1, bh, acc[1][cf]);
      acc[1][cf] = mfma16(al1, bh, acc[1][cf]);
      acc[1][cf] = mfma16(ah1, bl, acc[1][cf]);
    }
  }
#pragma unroll
  for (int cf = 0; cf < 4; ++cf) {
    float s = 0.f, s2 = 0.f;
    const int col = cf * 16 + lrow;
#pragma unroll
    for (int rf = 0; rf < 2; ++rf) {
      const int rbase = wrow + rf * 16 + (lane >> 4) * 4;
#pragma unroll
      for (int q = 0; q < 4; ++q) {
        float v = acc[rf][cf][q];
        y[(row0 + rbase + q) * 64 + col] = v;
        s += v; s2 += v * v;
      }
    }
    s += __shfl_xor(s, 16, 64); s += __shfl_xor(s, 32, 64);
    s2 += __shfl_xor(s2, 16, 64); s2 += __shfl_xor(s2, 32, 64);
    if ((lane >> 4) == 0) { swsum[wid][col] = s; swsq[wid][col] = s2; }
  }
  __syncthreads();
  if (t < 128) {
    const int c = t & 63;
    float v = (t < 64) ? (swsum[0][c] + swsum[1][c] + swsum[2][c] + swsum[3][c])
                       : (swsq[0][c] + swsq[1][c] + swsq[2][c] + swsq[3][c]);
    partial[(size_t)t * NBLK_ + blk] = v;
  }
}

// ---------------- layer 2: BN1+ReLU -> split GEMM 64->128 + fused max/min pool ----------------
__global__ __launch_bounds__(256) void layer2_kernel(
    const float* __restrict__ yin, const __bf16* __restrict__ wh,
    const __bf16* __restrict__ wl, const float* __restrict__ ab,
    float* __restrict__ ymax, float* __restrict__ ymin,
    float* __restrict__ partial) {
  __shared__ __align__(16) __bf16 Ah[128 * 72];
  __shared__ __align__(16) __bf16 Al[128 * 72];
  __shared__ __align__(16) __bf16 Bh[128 * 72];
  __shared__ __align__(16) __bf16 Bl[128 * 72];
  __shared__ float sa[64], sb[64];
  __shared__ float swsum[4][128], swsq[4][128];
  const int t = threadIdx.x;
  const int blk = blockIdx.x;
  const size_t row0 = (size_t)blk * 128;
  if (t < 64) { sa[t] = ab[t]; sb[t] = ab[128 + t]; }
  {
    const int4* sh4 = (const int4*)wh;
    const int4* sl4 = (const int4*)wl;
    int4* dh4 = (int4*)Bh;
    int4* dl4 = (int4*)Bl;
    for (int k = t; k < 1152; k += 256) { dh4[k] = sh4[k]; dl4[k] = sl4[k]; }
  }
  __syncthreads();
  {
    const int r = t >> 1, half = t & 1;
    const float4* s4 = (const float4*)(yin + (row0 + r) * 64 + half * 32);
#pragma unroll
    for (int j = 0; j < 4; ++j) {
      float4 u = s4[j * 2], w = s4[j * 2 + 1];
      float v[8] = {u.x, u.y, u.z, u.w, w.x, w.y, w.z, w.w};
#pragma unroll
      for (int e = 0; e < 8; ++e) {
        const int c = half * 32 + j * 8 + e;
        v[e] = fmaxf(v[e] * sa[c] + sb[c], 0.f);
      }
      bf16x8 hi, lo;
      split8(v, hi, lo);
      *(bf16x8*)(Ah + r * 72 + half * 32 + j * 8) = hi;
      *(bf16x8*)(Al + r * 72 + half * 32 + j * 8) = lo;
    }
  }
  __syncthreads();
  const int wid = t >> 6, lane = t & 63;
  const int wrow = wid * 32;
  const int lrow = lane & 15, lk = (lane >> 4) * 8;
  f32x4 acc[2][8];
#pragma unroll
  for (int a_ = 0; a_ < 2; ++a_)
#pragma unroll
    for (int b_ = 0; b_ < 8; ++b_) acc[a_][b_] = (f32x4){0.f, 0.f, 0.f, 0.f};
#pragma unroll
  for (int ks = 0; ks < 2; ++ks) {
    const int ko = ks * 32 + lk;
    bf16x8 ah0 = *(const bf16x8*)(Ah + (wrow + lrow) * 72 + ko);
    bf16x8 al0 = *(const bf16x8*)(Al + (wrow + lrow) * 72 + ko);
    bf16x8 ah1 = *(const bf16x8*)(Ah + (wrow + 16 + lrow) * 72 + ko);
    bf16x8 al1 = *(const bf16x8*)(Al + (wrow + 16 + lrow) * 72 + ko);
#pragma unroll
    for (int cf = 0; cf < 8; ++cf) {
      bf16x8 bh = *(const bf16x8*)(Bh + (cf * 16 + lrow) * 72 + ko);
      bf16x8 bl = *(const bf16x8*)(Bl + (cf * 16 + lrow) * 72 + ko);
      acc[0][cf] = mfma16(ah0, bh, acc[0][cf]);
      acc[0][cf] = mfma16(al0, bh, acc[0][cf]);
      acc[0][cf] = mfma16(ah0, bl, acc[0][cf]);
      acc[1][cf] = mfma16(ah1, bh, acc[1][cf]);
      acc[1][cf] = mfma16(al1, bh, acc[1][cf]);
      acc[1][cf] = mfma16(ah1, bl, acc[1][cf]);
    }
  }
  // each wave's 32 rows form exactly one (b,s) group
  const size_t bs = (size_t)blk * 4 + wid;
#pragma unroll
  for (int cf = 0; cf < 8; ++cf) {
    float s = 0.f, s2 = 0.f, mx = -3.4e38f, mn = 3.4e38f;
    const int col = cf * 16 + lrow;
#pragma unroll
    for (int rf = 0; rf < 2; ++rf)
#pragma unroll
      for (int q = 0; q < 4; ++q) {
        float v = acc[rf][cf][q];
        s += v; s2 += v * v;
        mx = fmaxf(mx, v); mn = fminf(mn, v);
      }
    s += __shfl_xor(s, 16, 64); s += __shfl_xor(s, 32, 64);
    s2 += __shfl_xor(s2, 16, 64); s2 += __shfl_xor(s2, 32, 64);
    mx = fmaxf(mx, __shfl_xor(mx, 16, 64)); mx = fmaxf(mx, __shfl_xor(mx, 32, 64));
    mn = fminf(mn, __shfl_xor(mn, 16, 64)); mn = fminf(mn, __shfl_xor(mn, 32, 64));
    if ((lane >> 4) == 0) {
      ymax[bs * 128 + col] = mx;
      ymin[bs * 128 + col] = mn;
      swsum[wid][col] = s; swsq[wid][col] = s2;
    }
  }
  __syncthreads();
  if (t < 128) {
    float v = swsum[0][t] + swsum[1][t] + swsum[2][t] + swsum[3][t];
    partial[(size_t)t * NBLK_ + blk] = v;
  } else {
    const int c = t - 128;
    float v = swsq[0][c] + swsq[1][c] + swsq[2][c] + swsq[3][c];
    partial[(size_t)t * NBLK_ + blk] = v;
  }
}

// ---------------- final: BN2+ReLU on pooled values ----------------
__global__ __launch_bounds__(256) void final_kernel(
    const float* __restrict__ ymax, const float* __restrict__ ymin,
    const float* __restrict__ ab, float* __restrict__ out) {
  const int gid = blockIdx.x * 256 + threadIdx.x;  // B*S*128
  const int col = gid & 127;
  const float a = ab[col];
  const float v = (a >= 0.f) ? ymax[gid] : ymin[gid];  // monotonicity of BN+ReLU vs sign(a)
  out[gid] = fmaxf(v * a + ab[128 + col], 0.f);
}

extern "C" void kernel_launch(void* const* d_in, const int* in_sizes, int n_in,
                              void* d_out, int out_size, void* d_ws, size_t ws_size,
                              hipStream_t stream) {
  const float* xyz = (const float*)d_in[0];
  const float* points = (const float*)d_in[1];
  const float* w0 = (const float*)d_in[2];
  const float* g0 = (const float*)d_in[4];
  const float* bt0 = (const float*)d_in[5];
  const float* w1 = (const float*)d_in[6];
  const float* g1 = (const float*)d_in[8];
  const float* bt1 = (const float*)d_in[9];
  const float* w2 = (const float*)d_in[10];
  const float* g2 = (const float*)d_in[12];
  const float* bt2 = (const float*)d_in[13];
  float* out = (float*)d_out;
  char* ws = (char*)d_ws;

  float4* sxyzp = (float4*)(ws + 0);       // 2 MB
  __bf16* w0h = (__bf16*)(ws + 2097152);   // 13312 B
  __bf16* w0l = (__bf16*)(ws + 2110464);
  __bf16* w1h = (__bf16*)(ws + 2123776);   // 9216 B
  __bf16* w1l = (__bf16*)(ws + 2132992);
  __bf16* w2h = (__bf16*)(ws + 2142208);   // 18432 B
  __bf16* w2l = (__bf16*)(ws + 2160640);
  int* idx    = (int*)(ws + 2179072);      // 2 MB
  float* y    = (float*)(ws + 4276224);    // 134217728 B (f32, reused L0->L1 in place)
  float* ymax = (float*)(ws + 138493952);  // 8388608
  float* ymin = (float*)(ws + 146882560);  // 8388608
  float* partial = (float*)(ws + 155271168); // 4194304
  float* ab   = (float*)(ws + 159465472);  // 3072
  if (ws_size < 159468544) return;

  prep_kernel<<<592, 256, 0, stream>>>(xyz, w0, w1, w2, sxyzp,
                                       w0h, w0l, w1h, w1l, w2h, w2l);
  fps_kernel<<<16, 512, 0, stream>>>(sxyzp, out);
  ballq_kernel<<<1024, 1024, 0, stream>>>(sxyzp, out, idx);
  layer0_kernel<<<NBLK_, 256, 0, stream>>>(sxyzp, points, out, idx, w0h, w0l, y, partial);
  stat_kernel<<<64, 64, 0, stream>>>(partial, g0, bt0, ab, 64);
  layer1_kernel<<<NBLK_, 256, 0, stream>>>(y, w1h, w1l, ab, partial);
  stat_kernel<<<64, 64, 0, stream>>>(partial, g1, bt1, ab + 256, 64);
  layer2_kernel<<<NBLK_, 256, 0, stream>>>(y, w2h, w2l, ab + 256, ymax, ymin, partial);
  stat_kernel<<<128, 64, 0, stream>>>(partial, g2, bt2, ab + 512, 128);
  final_kernel<<<8192, 256, 0, stream>>>(ymax, ymin, ab + 512, out + 49152);
}

// Round 12
// 1222.754 us; speedup vs baseline: 1.0753x; 1.0753x over previous
//
#include <hip/hip_runtime.h>

// PointNet++ Set Abstraction for MI355X (gfx950).
// prep -> FPS -> ball-query -> L0(mfma) -> stat -> L1 -> stat -> L2(+pool) -> stat -> final.
// FPS replicates reference f32 elementwise arithmetic exactly (non-FMA, same order).
// Ball-query dot uses an FMA chain replicating BLAS sgemm accumulation.
// Activations stored f32; GEMMs use hi/lo split-bf16 MFMA (near-f32).
// R11: revert to R9 (known best, 1221us): R10's forced pk-asm regressed 10%
// (operand-constraint copies + blocked scheduling) and ballq de-staging was
// neutral. R9 = no global stores in FPS loop (farhist in LDS), DPP wave-max,
// 512 thr x 16 pts.

typedef __bf16 bf16x8 __attribute__((ext_vector_type(8)));
typedef float f32x4 __attribute__((ext_vector_type(4)));
typedef float f32x2 __attribute__((ext_vector_type(2)));

#define B_ 16
#define N_ 8192
#define S_ 1024
#define K_ 32
#define M_ 524288   // B*S*K rows
#define NBLK_ 4096  // M/128

__device__ __forceinline__ f32x4 mfma16(bf16x8 a, bf16x8 b, f32x4 c) {
  return __builtin_amdgcn_mfma_f32_16x16x32_bf16(a, b, c, 0, 0, 0);
}

__device__ __forceinline__ void split8(const float* v, bf16x8& hi, bf16x8& lo) {
#pragma unroll
  for (int e = 0; e < 8; ++e) {
    __bf16 h = (__bf16)v[e];
    hi[e] = h;
    lo[e] = (__bf16)(v[e] - (float)h);
  }
}

// Wave64 max of non-negative f32 via DPP; returns uniform max (all lanes).
// bound_ctrl=true fills invalid lanes with 0 (max-neutral for x >= 0).
__device__ __forceinline__ float wave_max_nonneg(float x) {
  int v = __float_as_int(x);
#define DPP_MAX(ctrl)                                                          \
  v = __float_as_int(fmaxf(__int_as_float(v),                                  \
        __int_as_float(__builtin_amdgcn_update_dpp(0, v, (ctrl), 0xf, 0xf, true))))
  DPP_MAX(0x111);  // row_shr:1
  DPP_MAX(0x112);  // row_shr:2
  DPP_MAX(0x114);  // row_shr:4
  DPP_MAX(0x118);  // row_shr:8
  DPP_MAX(0x142);  // row_bcast:15
  DPP_MAX(0x143);  // row_bcast:31
#undef DPP_MAX
  return __int_as_float(__builtin_amdgcn_readlane(v, 63));
}

// ---------------- prep: packed {x,y,z,|p|^2}, hi/lo split weights ----------------
__global__ __launch_bounds__(256) void prep_kernel(
    const float* __restrict__ xyz, const float* __restrict__ w0,
    const float* __restrict__ w1, const float* __restrict__ w2,
    float4* __restrict__ sxyzp,
    __bf16* __restrict__ w0h, __bf16* __restrict__ w0l,
    __bf16* __restrict__ w1h, __bf16* __restrict__ w1l,
    __bf16* __restrict__ w2h, __bf16* __restrict__ w2l) {
#pragma clang fp contract(off)
  int gid = blockIdx.x * 256 + threadIdx.x;
  if (gid < B_ * N_) {
    float x = xyz[gid * 3 + 0], y = xyz[gid * 3 + 1], z = xyz[gid * 3 + 2];
    float p = (x * x + y * y) + z * z;  // exact reference order
    sxyzp[gid] = make_float4(x, y, z, p);
  } else {
    int j = gid - B_ * N_;
    float v; __bf16* ph; __bf16* pl; int jj;
    if (j < 6656) {            // W0: [64][104], real c<67
      int o = j / 104, c = j % 104;
      v = (c < 67) ? w0[o * 67 + c] : 0.f; ph = w0h; pl = w0l; jj = j;
    } else if (j < 6656 + 4608) {  // W1: [64][72], real c<64
      jj = j - 6656;
      int o = jj / 72, c = jj % 72;
      v = (c < 64) ? w1[o * 64 + c] : 0.f; ph = w1h; pl = w1l;
    } else if (j < 6656 + 4608 + 9216) {  // W2: [128][72]
      jj = j - 6656 - 4608;
      int o = jj / 72, c = jj % 72;
      v = (c < 64) ? w2[o * 64 + c] : 0.f; ph = w2h; pl = w2l;
    } else return;
    __bf16 h = (__bf16)v;
    ph[jj] = h;
    pl[jj] = (__bf16)(v - (float)h);
  }
}

// ---------------- FPS: one block per batch, 512 thr x 16 pts, DPP argmax ----------------
__global__ __launch_bounds__(512, 1) void fps_kernel(
    const float4* __restrict__ sxyzp, float* __restrict__ out /* new_xyz (B,S,3) */) {
#pragma clang fp contract(off)
  const int b = blockIdx.x;
  const int t = threadIdx.x;
  __shared__ float4 sp[N_];                    // 128 KB (centroid lookup)
  __shared__ int farhist[S_];                  // 4 KB winner history
  __shared__ uint2 went[2][8];                 // {val_bits, idx} per wave, double-buffered
  const float4* src = sxyzp + (size_t)b * N_;
  for (int i = t; i < N_; i += 512) sp[i] = src[i];
  __syncthreads();
  // contiguous chunk per lane: thread t owns points [16t, 16t+16), packed in pairs
  f32x2 px[8], py[8], pz[8], dd[8];
  const int i0 = t * 16;
#pragma unroll
  for (int w = 0; w < 16; ++w) {
    float4 v = sp[i0 + w];
    px[w >> 1][w & 1] = v.x; py[w >> 1][w & 1] = v.y; pz[w >> 1][w & 1] = v.z;
  }
#pragma unroll
  for (int j = 0; j < 8; ++j) dd[j] = (f32x2){1e10f, 1e10f};
  const int lane = t & 63, wid = t >> 6;
  int far = 0;
  for (int s = 0; s < S_; ++s) {
    if (t == 0) farhist[s] = far;              // LDS only; no global store in loop
    float4 c = sp[far];
    const f32x2 cx = {c.x, c.x}, cy = {c.y, c.y}, cz = {c.z, c.z};
    f32x2 bv2 = {-1.0f, -1.0f};
#pragma unroll
    for (int j = 0; j < 8; ++j) {
      f32x2 dx = px[j] - cx, dy = py[j] - cy, dz = pz[j] - cz;
      f32x2 d = (dx * dx + dy * dy) + dz * dz;  // exact reference order, no fma
      f32x2 nd = __builtin_elementwise_min(dd[j], d);
      dd[j] = nd;
      bv2 = __builtin_elementwise_max(bv2, nd);
    }
    float bv = fmaxf(bv2[0], bv2[1]);
    // first (lowest) local index equal to bv: descending select keeps lowest w
    int bi = 0;
#pragma unroll
    for (int w = 15; w >= 0; --w) if (dd[w >> 1][w & 1] == bv) bi = i0 + w;
    // wave-wide max via DPP (uniform), then lowest-lane index via SGPR readlane
    float m = wave_max_nonneg(bv);
    unsigned long long msk = __ballot(bv == m);
    int srcl = __ffsll((long long)msk) - 1;          // uniform (SGPR)
    int wbi = __builtin_amdgcn_readlane(bi, srcl);   // uniform
    if (lane == 0) went[s & 1][wid] = make_uint2(__float_as_uint(m), (unsigned)wbi);
    __syncthreads();
    // ascending wave scan, strict >: lowest wave (= lowest index) wins ties.
    // f32 order == u32 order for non-negative distances.
    uint2 bestE = went[s & 1][0];
#pragma unroll
    for (int w = 1; w < 8; ++w) {
      uint2 e = went[s & 1][w];
      if (e.x > bestE.x) bestE = e;
    }
    far = (int)bestE.y;
  }
  __syncthreads();
  // one-time output write from history (exact sp values)
  float* outB = out + (size_t)b * S_ * 3;
  for (int k = t; k < S_; k += 512) {
    float4 v = sp[farhist[k]];
    outB[k * 3 + 0] = v.x; outB[k * 3 + 1] = v.y; outB[k * 3 + 2] = v.z;
  }
}

// ---------------- ball query: 16 queries per block ----------------
__global__ __launch_bounds__(1024) void ballq_kernel(
    const float4* __restrict__ sxyzp, const float* __restrict__ newxyz,
    int* __restrict__ idxout) {
#pragma clang fp contract(off)
  __shared__ float4 sp[N_];                    // 128 KB
  __shared__ int sel[16][32];
  const int t = threadIdx.x;
  const int g = blockIdx.x;
  const int b = g >> 6;
  const int q0 = (g & 63) << 4;
  const float4* srcp = sxyzp + (size_t)b * N_;
  for (int i = t; i < N_; i += 1024) sp[i] = srcp[i];
  __syncthreads();
  const int wid = t >> 6, lane = t & 63;
  const int q = q0 + wid;
  const float* qp = newxyz + ((size_t)b * S_ + q) * 3;
  const float qx = qp[0], qy = qp[1], qz = qp[2];
  const float qq = (qx * qx + qy * qy) + qz * qz;
  const float rr = (float)(0.4 * 0.4);
  int nsel = 0;
  for (int c0 = 0; c0 < N_ && nsel < 32; c0 += 64) {
    int i = c0 + lane;
    float4 v = sp[i];
    // BLAS-style FMA accumulation chain (matches einsum->matmul lowering):
    float dot = fmaf(qz, v.z, fmaf(qy, v.y, qx * v.x));
    float d = -2.0f * dot;
    d = d + qq;
    d = d + v.w;
    unsigned long long m = __ballot(!(d > rr));
    if ((m >> lane) & 1ull) {
      int rank = nsel + __popcll(m & ((1ull << lane) - 1ull));
      if (rank < 32) sel[wid][rank] = i;
    }
    nsel += __popcll(m);
  }
  __syncthreads();
  int nv = nsel < 32 ? nsel : 32;
  int first = sel[wid][0];
  if (lane < 32)
    idxout[(((size_t)b * S_ + q) << 5) + lane] = (lane < nv) ? sel[wid][lane] : first;
}

// ---------------- layer 0: gather+concat -> split GEMM 67->64 (K padded 96) ----------------
__global__ __launch_bounds__(256) void layer0_kernel(
    const float4* __restrict__ sxyzp, const float* __restrict__ points,
    const float* __restrict__ newxyz, const int* __restrict__ idx,
    const __bf16* __restrict__ wh, const __bf16* __restrict__ wl,
    float* __restrict__ yout, float* __restrict__ partial) {
  __shared__ __align__(16) __bf16 Ah[128 * 104];
  __shared__ __align__(16) __bf16 Al[128 * 104];
  __shared__ __align__(16) __bf16 Bh[64 * 104];
  __shared__ __align__(16) __bf16 Bl[64 * 104];
  __shared__ float swsum[4][64], swsq[4][64];
  const int t = threadIdx.x;
  const int blk = blockIdx.x;
  const size_t row0 = (size_t)blk * 128;
  {
    const int4* sh4 = (const int4*)wh;
    const int4* sl4 = (const int4*)wl;
    int4* dh4 = (int4*)Bh;
    int4* dl4 = (int4*)Bl;
    for (int k = t; k < 832; k += 256) { dh4[k] = sh4[k]; dl4[k] = sl4[k]; }
  }
  {
    const int r = t >> 1, half = t & 1;
    const size_t row = row0 + r;
    const int b = (int)(row >> 15);
    const int s = (int)((row >> 5) & 1023);
    const int i = idx[row];
    const size_t bi = (size_t)b * N_ + i;
    const float* pt = points + bi * 64;
    const float* nx = newxyz + ((size_t)b * S_ + s) * 3;
    const int jb = half ? 6 : 0, je = half ? 13 : 6;
    float gx = 0.f, gy = 0.f, gz = 0.f;
    if (!half) {
      float4 xv = sxyzp[bi];
      gx = xv.x - nx[0]; gy = xv.y - nx[1]; gz = xv.z - nx[2];
    }
#pragma unroll 13
    for (int j = jb; j < je; ++j) {
      float v[8];
#pragma unroll
      for (int e = 0; e < 8; ++e) {
        const int c = j * 8 + e;
        v[e] = (c == 0) ? gx : (c == 1) ? gy : (c == 2) ? gz
               : (c < 67) ? pt[c - 3] : 0.f;
      }
      bf16x8 hi, lo;
      split8(v, hi, lo);
      *(bf16x8*)(Ah + r * 104 + j * 8) = hi;
      *(bf16x8*)(Al + r * 104 + j * 8) = lo;
    }
  }
  __syncthreads();
  const int wid = t >> 6, lane = t & 63;
  const int wrow = wid * 32;
  const int lrow = lane & 15, lk = (lane >> 4) * 8;
  f32x4 acc[2][4];
#pragma unroll
  for (int a_ = 0; a_ < 2; ++a_)
#pragma unroll
    for (int b_ = 0; b_ < 4; ++b_) acc[a_][b_] = (f32x4){0.f, 0.f, 0.f, 0.f};
#pragma unroll
  for (int ks = 0; ks < 3; ++ks) {
    const int ko = ks * 32 + lk;
    bf16x8 ah0 = *(const bf16x8*)(Ah + (wrow + lrow) * 104 + ko);
    bf16x8 al0 = *(const bf16x8*)(Al + (wrow + lrow) * 104 + ko);
    bf16x8 ah1 = *(const bf16x8*)(Ah + (wrow + 16 + lrow) * 104 + ko);
    bf16x8 al1 = *(const bf16x8*)(Al + (wrow + 16 + lrow) * 104 + ko);
#pragma unroll
    for (int cf = 0; cf < 4; ++cf) {
      bf16x8 bh = *(const bf16x8*)(Bh + (cf * 16 + lrow) * 104 + ko);
      bf16x8 bl = *(const bf16x8*)(Bl + (cf * 16 + lrow) * 104 + ko);
      acc[0][cf] = mfma16(ah0, bh, acc[0][cf]);
      acc[0][cf] = mfma16(al0, bh, acc[0][cf]);
      acc[0][cf] = mfma16(ah0, bl, acc[0][cf]);
      acc[1][cf] = mfma16(ah1, bh, acc[1][cf]);
      acc[1][cf] = mfma16(al1, bh, acc[1][cf]);
      acc[1][cf] = mfma16(ah1, bl, acc[1][cf]);
    }
  }
#pragma unroll
  for (int cf = 0; cf < 4; ++cf) {
    float s = 0.f, s2 = 0.f;
    const int col = cf * 16 + lrow;
#pragma unroll
    for (int rf = 0; rf < 2; ++rf) {
      const int rbase = wrow + rf * 16 + (lane >> 4) * 4;
#pragma unroll
      for (int q = 0; q < 4; ++q) {
        float v = acc[rf][cf][q];
        yout[(row0 + rbase + q) * 64 + col] = v;
        s += v; s2 += v * v;
      }
    }
    s += __shfl_xor(s, 16, 64); s += __shfl_xor(s, 32, 64);
    s2 += __shfl_xor(s2, 16, 64); s2 += __shfl_xor(s2, 32, 64);
    if ((lane >> 4) == 0) { swsum[wid][col] = s; swsq[wid][col] = s2; }
  }
  __syncthreads();
  if (t < 128) {
    const int c = t & 63;
    float v = (t < 64) ? (swsum[0][c] + swsum[1][c] + swsum[2][c] + swsum[3][c])
                       : (swsq[0][c] + swsq[1][c] + swsq[2][c] + swsq[3][c]);
    partial[(size_t)t * NBLK_ + blk] = v;
  }
}

// ---------------- stat: mean/var -> (a, shift) ----------------
__global__ __launch_bounds__(64) void stat_kernel(
    const float* __restrict__ partial, const float* __restrict__ g,
    const float* __restrict__ bt, float* __restrict__ ab, int nch) {
  const int o = blockIdx.x, t = threadIdx.x;
  float s = 0.f, s2 = 0.f;
  for (int i = t; i < NBLK_; i += 64) {
    s += partial[(size_t)o * NBLK_ + i];
    s2 += partial[(size_t)(nch + o) * NBLK_ + i];
  }
#pragma unroll
  for (int off = 32; off >= 1; off >>= 1) {
    s += __shfl_xor(s, off, 64);
    s2 += __shfl_xor(s2, off, 64);
  }
  if (t == 0) {
    const float minv = 1.0f / (float)M_;
    float mean = s * minv;
    float var = s2 * minv - mean * mean;
    float a = g[o] * rsqrtf(var + 1e-5f);
    ab[o] = a;
    ab[128 + o] = bt[o] - mean * a;
  }
}

// ---------------- layer 1: BN0+ReLU on load -> split GEMM 64->64 (in-place y) ----------------
__global__ __launch_bounds__(256) void layer1_kernel(
    float* y /* f32 activations, read rows then overwritten (same block) */,
    const __bf16* __restrict__ wh, const __bf16* __restrict__ wl,
    const float* __restrict__ ab, float* __restrict__ partial) {
  __shared__ __align__(16) __bf16 Ah[128 * 72];
  __shared__ __align__(16) __bf16 Al[128 * 72];
  __shared__ __align__(16) __bf16 Bh[64 * 72];
  __shared__ __align__(16) __bf16 Bl[64 * 72];
  __shared__ float sa[64], sb[64];
  __shared__ float swsum[4][64], swsq[4][64];
  const int t = threadIdx.x;
  const int blk = blockIdx.x;
  const size_t row0 = (size_t)blk * 128;
  if (t < 64) { sa[t] = ab[t]; sb[t] = ab[128 + t]; }
  {
    const int4* sh4 = (const int4*)wh;
    const int4* sl4 = (const int4*)wl;
    int4* dh4 = (int4*)Bh;
    int4* dl4 = (int4*)Bl;
    for (int k = t; k < 576; k += 256) { dh4[k] = sh4[k]; dl4[k] = sl4[k]; }
  }
  __syncthreads();
  {
    const int r = t >> 1, half = t & 1;
    const float4* s4 = (const float4*)(y + (row0 + r) * 64 + half * 32);
#pragma unroll
    for (int j = 0; j < 4; ++j) {
      float4 u = s4[j * 2], w = s4[j * 2 + 1];
      float v[8] = {u.x, u.y, u.z, u.w, w.x, w.y, w.z, w.w};
#pragma unroll
      for (int e = 0; e < 8; ++e) {
        const int c = half * 32 + j * 8 + e;
        v[e] = fmaxf(v[e] * sa[c] + sb[c], 0.f);
      }
      bf16x8 hi, lo;
      split8(v, hi, lo);
      *(bf16x8*)(Ah + r * 72 + half * 32 + j * 8) = hi;
      *(bf16x8*)(Al + r * 72 + half * 32 + j * 8) = lo;
    }
  }
  __syncthreads();
  const int wid = t >> 6, lane = t & 63;
  const int wrow = wid * 32;
  const int lrow = lane & 15, lk = (lane >> 4) * 8;
  f32x4 acc[2][4];
#pragma unroll
  for (int a_ = 0; a_ < 2; ++a_)
#pragma unroll
    for (int b_ = 0; b_ < 4; ++b_) acc[a_][b_] = (f32x4){0.f, 0.f, 0.f, 0.f};
#pragma unroll
  for (int ks = 0; ks < 2; ++ks) {
    const int ko = ks * 32 + lk;
    bf16x8 ah0 = *(const bf16x8*)(Ah + (wrow + lrow) * 72 + ko);
    bf16x8 al0 = *(const bf16x8*)(Al + (wrow + lrow) * 72 + ko);
    bf16x8 ah1 = *(const bf16x8*)(Ah + (wrow + 16 + lrow) * 72 + ko);
    bf16x8 al1 = *(const bf16x8*)(Al + (wrow + 16 + lrow) * 72 + ko);
#pragma unroll
    for (int cf = 0; cf < 4; ++cf) {
      bf16x8 bh = *(const bf16x8*)(Bh + (cf * 16 + lrow) * 72 + ko);
      bf16x8 bl = *(const bf16x8*)(Bl + (cf * 16 + lrow) * 72 + ko);
      acc[0][cf] = mfma16(ah0, bh, acc[0][cf]);
      acc[0][cf] = mfma16(al0, bh, acc[0][cf]);
      acc[0][cf] = mfma16(ah0, bl, acc[0][cf]);
      acc[1][cf] = mfma16(ah1, bh, acc[1][cf]);
      acc[1][cf] = mfma16(al1, bh, acc[1][cf]);
      acc[1][cf] = mfma16(ah1, bl, acc[1][cf]);
    }
  }
#pragma unroll
  for (int cf = 0; cf < 4; ++cf) {
    float s = 0.f, s2 = 0.f;
    const int col = cf * 16 + lrow;
#pragma unroll
    for (int rf = 0; rf < 2; ++rf) {
      const int rbase = wrow + rf * 16 + (lane >> 4) * 4;
#pragma unroll
      for (int q = 0; q < 4; ++q) {
        float v = acc[rf][cf][q];
        y[(row0 + rbase + q) * 64 + col] = v;
        s += v; s2 += v * v;
      }
    }
    s += __shfl_xor(s, 16, 64); s += __shfl_xor(s, 32, 64);
    s2 += __shfl_xor(s2, 16, 64); s2 += __shfl_xor(s2, 32, 64);
    if ((lane >> 4) == 0) { swsum[wid][col] = s; swsq[wid][col] = s2; }
  }
  __syncthreads();
  if (t < 128) {
    const int c = t & 63;
    float v = (t < 64) ? (swsum[0][c] + swsum[1][c] + swsum[2][c] + swsum[3][c])
                       : (swsq[0][c] + swsq[1][c] + swsq[2][c] + swsq[3][c]);
    partial[(size_t)t * NBLK_ + blk] = v;
  }
}

// ---------------- layer 2: BN1+ReLU -> split GEMM 64->128 + fused max/min pool ----------------
__global__ __launch_bounds__(256) void layer2_kernel(
    const float* __restrict__ yin, const __bf16* __restrict__ wh,
    const __bf16* __restrict__ wl, const float* __restrict__ ab,
    float* __restrict__ ymax, float* __restrict__ ymin,
    float* __restrict__ partial) {
  __shared__ __align__(16) __bf16 Ah[128 * 72];
  __shared__ __align__(16) __bf16 Al[128 * 72];
  __shared__ __align__(16) __bf16 Bh[128 * 72];
  __shared__ __align__(16) __bf16 Bl[128 * 72];
  __shared__ float sa[64], sb[64];
  __shared__ float swsum[4][128], swsq[4][128];
  const int t = threadIdx.x;
  const int blk = blockIdx.x;
  const size_t row0 = (size_t)blk * 128;
  if (t < 64) { sa[t] = ab[t]; sb[t] = ab[128 + t]; }
  {
    const int4* sh4 = (const int4*)wh;
    const int4* sl4 = (const int4*)wl;
    int4* dh4 = (int4*)Bh;
    int4* dl4 = (int4*)Bl;
    for (int k = t; k < 1152; k += 256) { dh4[k] = sh4[k]; dl4[k] = sl4[k]; }
  }
  __syncthreads();
  {
    const int r = t >> 1, half = t & 1;
    const float4* s4 = (const float4*)(yin + (row0 + r) * 64 + half * 32);
#pragma unroll
    for (int j = 0; j < 4; ++j) {
      float4 u = s4[j * 2], w = s4[j * 2 + 1];
      float v[8] = {u.x, u.y, u.z, u.w, w.x, w.y, w.z, w.w};
#pragma unroll
      for (int e = 0; e < 8; ++e) {
        const int c = half * 32 + j * 8 + e;
        v[e] = fmaxf(v[e] * sa[c] + sb[c], 0.f);
      }
      bf16x8 hi, lo;
      split8(v, hi, lo);
      *(bf16x8*)(Ah + r * 72 + half * 32 + j * 8) = hi;
      *(bf16x8*)(Al + r * 72 + half * 32 + j * 8) = lo;
    }
  }
  __syncthreads();
  const int wid = t >> 6, lane = t & 63;
  const int wrow = wid * 32;
  const int lrow = lane & 15, lk = (lane >> 4) * 8;
  f32x4 acc[2][8];
#pragma unroll
  for (int a_ = 0; a_ < 2; ++a_)
#pragma unroll
    for (int b_ = 0; b_ < 8; ++b_) acc[a_][b_] = (f32x4){0.f, 0.f, 0.f, 0.f};
#pragma unroll
  for (int ks = 0; ks < 2; ++ks) {
    const int ko = ks * 32 + lk;
    bf16x8 ah0 = *(const bf16x8*)(Ah + (wrow + lrow) * 72 + ko);
    bf16x8 al0 = *(const bf16x8*)(Al + (wrow + lrow) * 72 + ko);
    bf16x8 ah1 = *(const bf16x8*)(Ah + (wrow + 16 + lrow) * 72 + ko);
    bf16x8 al1 = *(const bf16x8*)(Al + (wrow + 16 + lrow) * 72 + ko);
#pragma unroll
    for (int cf = 0; cf < 8; ++cf) {
      bf16x8 bh = *(const bf16x8*)(Bh + (cf * 16 + lrow) * 72 + ko);
      bf16x8 bl = *(const bf16x8*)(Bl + (cf * 16 + lrow) * 72 + ko);
      acc[0][cf] = mfma16(ah0, bh, acc[0][cf]);
      acc[0][cf] = mfma16(al0, bh, acc[0][cf]);
      acc[0][cf] = mfma16(ah0, bl, acc[0][cf]);
      acc[1][cf] = mfma16(ah1, bh, acc[1][cf]);
      acc[1][cf] = mfma16(al1, bh, acc[1][cf]);
      acc[1][cf] = mfma16(ah1, bl, acc[1][cf]);
    }
  }
  // each wave's 32 rows form exactly one (b,s) group
  const size_t bs = (size_t)blk * 4 + wid;
#pragma unroll
  for (int cf = 0; cf < 8; ++cf) {
    float s = 0.f, s2 = 0.f, mx = -3.4e38f, mn = 3.4e38f;
    const int col = cf * 16 + lrow;
#pragma unroll
    for (int rf = 0; rf < 2; ++rf)
#pragma unroll
      for (int q = 0; q < 4; ++q) {
        float v = acc[rf][cf][q];
        s += v; s2 += v * v;
        mx = fmaxf(mx, v); mn = fminf(mn, v);
      }
    s += __shfl_xor(s, 16, 64); s += __shfl_xor(s, 32, 64);
    s2 += __shfl_xor(s2, 16, 64); s2 += __shfl_xor(s2, 32, 64);
    mx = fmaxf(mx, __shfl_xor(mx, 16, 64)); mx = fmaxf(mx, __shfl_xor(mx, 32, 64));
    mn = fminf(mn, __shfl_xor(mn, 16, 64)); mn = fminf(mn, __shfl_xor(mn, 32, 64));
    if ((lane >> 4) == 0) {
      ymax[bs * 128 + col] = mx;
      ymin[bs * 128 + col] = mn;
      swsum[wid][col] = s; swsq[wid][col] = s2;
    }
  }
  __syncthreads();
  if (t < 128) {
    float v = swsum[0][t] + swsum[1][t] + swsum[2][t] + swsum[3][t];
    partial[(size_t)t * NBLK_ + blk] = v;
  } else {
    const int c = t - 128;
    float v = swsq[0][c] + swsq[1][c] + swsq[2][c] + swsq[3][c];
    partial[(size_t)t * NBLK_ + blk] = v;
  }
}

// ---------------- final: BN2+ReLU on pooled values ----------------
__global__ __launch_bounds__(256) void final_kernel(
    const float* __restrict__ ymax, const float* __restrict__ ymin,
    const float* __restrict__ ab, float* __restrict__ out) {
  const int gid = blockIdx.x * 256 + threadIdx.x;  // B*S*128
  const int col = gid & 127;
  const float a = ab[col];
  const float v = (a >= 0.f) ? ymax[gid] : ymin[gid];  // monotonicity of BN+ReLU vs sign(a)
  out[gid] = fmaxf(v * a + ab[128 + col], 0.f);
}

extern "C" void kernel_launch(void* const* d_in, const int* in_sizes, int n_in,
                              void* d_out, int out_size, void* d_ws, size_t ws_size,
                              hipStream_t stream) {
  const float* xyz = (const float*)d_in[0];
  const float* points = (const float*)d_in[1];
  const float* w0 = (const float*)d_in[2];
  const float* g0 = (const float*)d_in[4];
  const float* bt0 = (const float*)d_in[5];
  const float* w1 = (const float*)d_in[6];
  const float* g1 = (const float*)d_in[8];
  const float* bt1 = (const float*)d_in[9];
  const float* w2 = (const float*)d_in[10];
  const float* g2 = (const float*)d_in[12];
  const float* bt2 = (const float*)d_in[13];
  float* out = (float*)d_out;
  char* ws = (char*)d_ws;

  float4* sxyzp = (float4*)(ws + 0);       // 2 MB
  __bf16* w0h = (__bf16*)(ws + 2097152);   // 13312 B
  __bf16* w0l = (__bf16*)(ws + 2110464);
  __bf16* w1h = (__bf16*)(ws + 2123776);   // 9216 B
  __bf16* w1l = (__bf16*)(ws + 2132992);
  __bf16* w2h = (__bf16*)(ws + 2142208);   // 18432 B
  __bf16* w2l = (__bf16*)(ws + 2160640);
  int* idx    = (int*)(ws + 2179072);      // 2 MB
  float* y    = (float*)(ws + 4276224);    // 134217728 B (f32, reused L0->L1 in place)
  float* ymax = (float*)(ws + 138493952);  // 8388608
  float* ymin = (float*)(ws + 146882560);  // 8388608
  float* partial = (float*)(ws + 155271168); // 4194304
  float* ab   = (float*)(ws + 159465472);  // 3072
  if (ws_size < 159468544) return;

  prep_kernel<<<592, 256, 0, stream>>>(xyz, w0, w1, w2, sxyzp,
                                       w0h, w0l, w1h, w1l, w2h, w2l);
  fps_kernel<<<16, 512, 0, stream>>>(sxyzp, out);
  ballq_kernel<<<1024, 1024, 0, stream>>>(sxyzp, out, idx);
  layer0_kernel<<<NBLK_, 256, 0, stream>>>(sxyzp, points, out, idx, w0h, w0l, y, partial);
  stat_kernel<<<64, 64, 0, stream>>>(partial, g0, bt0, ab, 64);
  layer1_kernel<<<NBLK_, 256, 0, stream>>>(y, w1h, w1l, ab, partial);
  stat_kernel<<<64, 64, 0, stream>>>(partial, g1, bt1, ab + 256, 64);
  layer2_kernel<<<NBLK_, 256, 0, stream>>>(y, w2h, w2l, ab + 256, ymax, ymin, partial);
  stat_kernel<<<128, 64, 0, stream>>>(partial, g2, bt2, ab + 512, 128);
  final_kernel<<<8192, 256, 0, stream>>>(ymax, ymin, ab + 512, out + 49152);
}